// Round 7
// baseline (1448.449 us; speedup 1.0000x reference)
//
#include <hip/hip_runtime.h>
#include <hip/hip_fp16.h>

// Problem constants (fixed by the reference)
#define NUu 100000
#define NIi 50000
#define NEe 2000000
// D = DIN = 64, NB = 2, NC = 5
#define QSCALE 512.0f
#define QINV   (1.0f / 512.0f)

#define NSH   8        // XCD shards
#define NBUK  64       // (dst_shard, src_shard) buckets
#define NBLK  512      // binning blocks
#define NTICK 4096     // tickets per pool (8 sub-buckets x 512 runs)
#define ISH   6250     // NI / 8
#define USH   12500    // NU / 8

__device__ __forceinline__ int get_xcc_id() {
    int x;
    asm("s_getreg_b32 %0, hwreg(HW_REG_XCC_ID)" : "=s"(x));
    return x & 7;
}

// msg row -> quantized int16x4 packed into u64[16] per row.
__global__ __launch_bounds__(256) void gemm64_enc(
    const float* __restrict__ feat, const float* __restrict__ W,
    const float* __restrict__ cvec, unsigned long long* __restrict__ enc, int N)
{
    __shared__ float Wl[64 * 64];
    __shared__ float rows[16][64];
    __shared__ short q[16][64];
    const int tid = threadIdx.x;
    for (int i = tid; i < 4096; i += 256) Wl[i] = W[i];
    const int r0 = blockIdx.x * 16;
    for (int i = tid; i < 16 * 64; i += 256) {
        int r = r0 + (i >> 6);
        rows[i >> 6][i & 63] = (r < N) ? feat[(size_t)r * 64 + (i & 63)] : 0.f;
    }
    __syncthreads();
    const int col = tid & 63;
    const int rq  = tid >> 6;
    for (int rr = rq; rr < 16; rr += 4) {
        int r = r0 + rr;
        if (r >= N) continue;
        float s = 0.f;
        #pragma unroll
        for (int k = 0; k < 64; ++k)
            s = fmaf(rows[rr][k], Wl[k * 64 + col], s);
        int qv = (int)lrintf(s * cvec[r] * QSCALE);
        qv = max(-32768, min(32767, qv));
        q[rr][col] = (short)qv;
    }
    __syncthreads();
    const int row = tid >> 4;
    const int j   = tid & 15;
    int r = r0 + row;
    if (r < N) {
        long long v = (long long)q[row][4 * j]
                    + ((long long)q[row][4 * j + 1] << 16)
                    + ((long long)q[row][4 * j + 2] << 32)
                    + ((long long)q[row][4 * j + 3] << 48);
        enc[(size_t)r * 16 + j] = (unsigned long long)v;
    }
}

__device__ __forceinline__ int bucket_of(int s, int d) {
    return (d / ISH) * 8 + (s / USH);   // dst-shard major
}

// K1: per-block 64-bucket histogram of its edge chunk
__global__ __launch_bounds__(256) void bin_hist(
    const int* __restrict__ src, const int* __restrict__ dst,
    int* __restrict__ counts, int chunk)
{
    __shared__ int cnt[NBUK];
    const int tid = threadIdx.x;
    if (tid < NBUK) cnt[tid] = 0;
    __syncthreads();
    const int beg = blockIdx.x * chunk;
    const int end = min(NEe, beg + chunk);
    for (int t = beg + tid; t < end; t += 256)
        atomicAdd(&cnt[bucket_of(src[t], dst[t])], 1);
    __syncthreads();
    if (tid < NBUK) counts[blockIdx.x * NBUK + tid] = cnt[tid];
}

// K2: bucket bases + per-(block,bucket) slot bases + rowptr
__global__ __launch_bounds__(256) void bin_scan(
    const int* __restrict__ counts, int* __restrict__ slotbase,
    int* __restrict__ rowptr)
{
    __shared__ int tot[NBUK];
    __shared__ int base[NBUK];
    const int tid = threadIdx.x;
    if (tid < NBUK) {
        int s = 0;
        for (int b = 0; b < NBLK; ++b) s += counts[b * NBUK + tid];
        tot[tid] = s;
    }
    __syncthreads();
    if (tid == 0) {
        int run = 0;
        for (int j = 0; j < NBUK; ++j) { base[j] = run; run += tot[j]; }
    }
    __syncthreads();
    if (tid < NBUK) {
        int run = base[tid];
        for (int b = 0; b < NBLK; ++b) {
            slotbase[b * NBUK + tid] = run;
            run += counts[b * NBUK + tid];
        }
        rowptr[tid] = base[tid];
        if (tid == 0) rowptr[NBUK] = NEe;
    }
}

// K3: scatter edges into exact bucket slots (SoA)
__global__ __launch_bounds__(256) void bin_fill(
    const int* __restrict__ src, const int* __restrict__ dst,
    const int* __restrict__ slotbase,
    int* __restrict__ bsrc, int* __restrict__ bdst, int chunk)
{
    __shared__ int cur[NBUK];
    const int tid = threadIdx.x;
    if (tid < NBUK) cur[tid] = slotbase[blockIdx.x * NBUK + tid];
    __syncthreads();
    const int beg = blockIdx.x * chunk;
    const int end = min(NEe, beg + chunk);
    for (int t = beg + tid; t < end; t += 256) {
        int s = src[t], d = dst[t];
        int p = atomicAdd(&cur[bucket_of(s, d)], 1);
        bsrc[p] = s;
        bdst[p] = d;
    }
}

// XCD-sharded scatter. ITEM_SIDE: buckets 8*xcc+j, gather msg[src], acc[dst].
// USER_SIDE: buckets 8*j+xcc, gather msg[dst], acc[src]. Workgroup-scope u64
// atomics: every writer of shard xcc runs on XCD xcc -> RMW stays in that
// XCD's L2 (correct: same L2 serializes; end-of-kernel release publishes).
// Coverage is guaranteed by ticket exhaustion, not by dispatch heuristics.
template <int ITEM_SIDE>
__global__ __launch_bounds__(256) void scatter_shard(
    const int* __restrict__ bsrc, const int* __restrict__ bdst,
    const int* __restrict__ rowptr,
    const unsigned long long* __restrict__ msg,
    unsigned long long* __restrict__ acc,
    int* __restrict__ tickets)
{
    const int xcc  = get_xcc_id();
    const int lane = threadIdx.x & 63;
    const int q    = lane >> 4;          // edge within quad
    const int f    = lane & 15;          // u64 index within row
    int t;
    for (;;) {
        if (lane == 0) t = atomicAdd(&tickets[xcc], 1);
        t = __shfl(t, 0, 64);
        if (t >= NTICK) break;
        const int j   = t & 7;
        const int sub = t >> 3;          // 0..511
        const int b   = ITEM_SIDE ? (8 * xcc + j) : (8 * j + xcc);
        const int beg = rowptr[b], end = rowptr[b + 1];
        const int sz  = end - beg;
        const int R   = (sz + 511) >> 9;
        const int lo  = beg + sub * R;
        const int hi  = min(lo + R, end);
        for (int i0 = lo; i0 < hi; i0 += 4) {
            int i = i0 + q;
            if (i < hi) {
                int s = bsrc[i], d = bdst[i];
                int gn = ITEM_SIDE ? s : d;   // gather node
                int an = ITEM_SIDE ? d : s;   // accumulate node
                unsigned long long v = msg[(size_t)gn * 16 + f];
                __hip_atomic_fetch_add(&acc[(size_t)an * 16 + f], v,
                                       __ATOMIC_RELAXED, __HIP_MEMORY_SCOPE_WORKGROUP);
            }
        }
    }
}

// Decode packed accumulators -> fp16 rows (x 1/QSCALE)
__global__ __launch_bounds__(256) void decode_h(
    const unsigned long long* __restrict__ acc, __half2* __restrict__ out, int n)
{
    int i = blockIdx.x * 256 + threadIdx.x;
    if (i >= n) return;
    long long tt = (long long)acc[i];
    int s0 = (short)(tt & 0xffff); tt = (tt - s0) >> 16;
    int s1 = (short)(tt & 0xffff); tt = (tt - s1) >> 16;
    int s2 = (short)(tt & 0xffff); tt = (tt - s2) >> 16;
    int s3 = (short)(tt & 0xffff);
    out[2 * i]     = __floats2half2_rn(s0 * QINV, s1 * QINV);
    out[2 * i + 1] = __floats2half2_rn(s2 * QINV, s3 * QINV);
}

// hb[m,b,d] = half( c_i[m] * sum_k h[m,k] * P[b,d,k] )
__global__ __launch_bounds__(256) void basis_projT_h(
    const __half* __restrict__ h, const float* __restrict__ P,
    const float* __restrict__ ci, __half* __restrict__ hb, int N)
{
    __shared__ float Pl[2 * 64 * 65];
    __shared__ float rows[8][64];
    const int tid = threadIdx.x;
    for (int i = tid; i < 8192; i += 256) {
        int b = i >> 12, rem = i & 4095, dg = rem >> 6, kg = rem & 63;
        Pl[b * 4160 + kg * 65 + dg] = P[i];
    }
    const int r0 = blockIdx.x * 8;
    for (int i = tid; i < 512; i += 256) {
        int r = r0 + (i >> 6);
        rows[i >> 6][i & 63] = (r < N) ? __half2float(h[(size_t)r * 64 + (i & 63)]) : 0.f;
    }
    __syncthreads();
    const int col = tid & 63;
    const int b   = (tid >> 6) & 1;
    const int rh  = tid >> 7;
    for (int rr = rh; rr < 8; rr += 2) {
        int r = r0 + rr;
        if (r >= N) continue;
        float s = 0.f;
        #pragma unroll
        for (int k = 0; k < 64; ++k)
            s = fmaf(rows[rr][k], Pl[b * 4160 + k * 65 + col], s);
        hb[((size_t)r * 2 + b) * 64 + col] = __float2half(s * ci[r]);
    }
}

// out[e,c] = c_u[src] * sum_b (h_user[src,:].hib[dst,b,:]) * Wc[c,b]
__global__ __launch_bounds__(256) void edge_out_h(
    const uint2* __restrict__ hu, const uint2* __restrict__ hib,
    const int* __restrict__ src, const int* __restrict__ dst,
    const float* __restrict__ cu, const float* __restrict__ Wc,
    float* __restrict__ out, int nquads)
{
    const int l   = threadIdx.x & 63;
    const int q   = l >> 4;
    const int j   = l & 15;
    const int wid = blockIdx.x * 4 + (threadIdx.x >> 6);
    const int nw  = gridDim.x * 4;
    const float wcA = (j < 5) ? Wc[2 * j]     : 0.f;
    const float wcB = (j < 5) ? Wc[2 * j + 1] : 0.f;
    for (int t = wid; t < nquads; t += nw) {
        int e = t * 4 + q;
        int s = src[e], d = dst[e];
        uint2 ua = hu[(size_t)s * 16 + j];
        uint2 b0 = hib[(size_t)d * 32 + j];
        uint2 b1 = hib[(size_t)d * 32 + 16 + j];
        float2 u0 = __half22float2(*(const __half2*)&ua.x);
        float2 u1 = __half22float2(*(const __half2*)&ua.y);
        float2 v0 = __half22float2(*(const __half2*)&b0.x);
        float2 v1 = __half22float2(*(const __half2*)&b0.y);
        float2 w0 = __half22float2(*(const __half2*)&b1.x);
        float2 w1 = __half22float2(*(const __half2*)&b1.y);
        float p0 = u0.x * v0.x + u0.y * v0.y + u1.x * v1.x + u1.y * v1.y;
        float p1 = u0.x * w0.x + u0.y * w0.y + u1.x * w1.x + u1.y * w1.y;
        #pragma unroll
        for (int m = 1; m < 16; m <<= 1) {
            p0 += __shfl_xor(p0, m, 64);
            p1 += __shfl_xor(p1, m, 64);
        }
        if (j < 5) out[(size_t)e * 5 + j] = (p0 * wcA + p1 * wcB) * cu[s];
    }
}

extern "C" void kernel_launch(void* const* d_in, const int* in_sizes, int n_in,
                              void* d_out, int out_size, void* d_ws, size_t ws_size,
                              hipStream_t stream) {
    const float* ufeat  = (const float*)d_in[0];
    const float* ifeat  = (const float*)d_in[1];
    const float* c_u    = (const float*)d_in[2];
    const float* c_i    = (const float*)d_in[3];
    const float* W_user = (const float*)d_in[4];
    const float* W_item = (const float*)d_in[5];
    const float* P      = (const float*)d_in[6];
    const float* Wc     = (const float*)d_in[7];
    const int*   src    = (const int*)d_in[8];
    const int*   dst    = (const int*)d_in[9];
    float* out = (float*)d_out;
    char*  ws  = (char*)d_ws;

    // Workspace layout (bytes):
    unsigned long long* acc_item  = (unsigned long long*)(ws);              //  6,400,000
    unsigned long long* acc_user  = (unsigned long long*)(ws +  6400000);   // 12,800,000
    int*   tickets   = (int*)(ws + 19200000);                               //         64
    int*   counts    = (int*)(ws + 19200064);                               //    131,072
    int*   slotbase  = (int*)(ws + 19331136);                               //    131,072
    int*   rowptr    = (int*)(ws + 19462208);                               //        512
    int*   bsrc      = (int*)(ws + 19462720);                               //  8,000,000
    int*   bdst      = (int*)(ws + 27462720);                               //  8,000,000
    unsigned long long* msg_u_enc = (unsigned long long*)(ws + 35462720);   // 12,800,000
    unsigned long long* msg_i_enc = (unsigned long long*)(ws + 48262720);   //  6,400,000
    __half* h_item = (__half*)(ws + 54662720);                              //  6,400,000
    __half* h_user = (__half*)(ws + 61062720);                              // 12,800,000 (contiguous after h_item)
    __half* hi_b   = (__half*)(ws + 73862720);                              // 12,800,000
    // total 86,662,720 bytes

    // Zero accumulators + ticket pools (d_ws poisoned once, never restored)
    (void)hipMemsetAsync(ws, 0, 19200064, stream);

    const int chunk = (NEe + NBLK - 1) / NBLK;

    // Bin edges into 64 (dst_shard, src_shard) buckets
    bin_hist<<<NBLK, 256, 0, stream>>>(src, dst, counts, chunk);
    bin_scan<<<1, 256, 0, stream>>>(counts, slotbase, rowptr);
    bin_fill<<<NBLK, 256, 0, stream>>>(src, dst, slotbase, bsrc, bdst, chunk);

    // messages, pre-quantized+packed
    gemm64_enc<<<(NUu + 15) / 16, 256, 0, stream>>>(ufeat, W_user, c_u, msg_u_enc, NUu);
    gemm64_enc<<<(NIi + 15) / 16, 256, 0, stream>>>(ifeat, W_item, c_i, msg_i_enc, NIi);

    // XCD-sharded scatters (workgroup-scope = L2-local atomics)
    scatter_shard<1><<<2048, 256, 0, stream>>>(bsrc, bdst, rowptr, msg_u_enc, acc_item, tickets);
    scatter_shard<0><<<2048, 256, 0, stream>>>(bsrc, bdst, rowptr, msg_i_enc, acc_user, tickets + 8);

    // decode acc_item||acc_user -> h_item||h_user (contiguous)
    {
        int n = (NIi + NUu) * 16;
        decode_h<<<(n + 255) / 256, 256, 0, stream>>>(acc_item, (__half2*)h_item, n);
    }

    basis_projT_h<<<(NIi + 7) / 8, 256, 0, stream>>>(h_item, P, c_i, hi_b, NIi);
    edge_out_h<<<2048, 256, 0, stream>>>(
        (const uint2*)h_user, (const uint2*)hi_b, src, dst, c_u, Wc, out, NEe / 4);
}